// Round 13
// baseline (572.974 us; speedup 1.0000x reference)
//
#include <hip/hip_runtime.h>

typedef __bf16 bf16;
typedef __bf16 bf16x4 __attribute__((ext_vector_type(4)));
typedef __bf16 bf16x8 __attribute__((ext_vector_type(8)));
typedef float f32x4 __attribute__((ext_vector_type(4)));
typedef float f32x2 __attribute__((ext_vector_type(2)));

#define S 2048
#define DM 2048
#define HD 128
#define H 16
#define NQKV 3072
#define AS_ITERS 3
#define NW_ITERS 3
#define BROW 556  // f32 row stride of attn LDS buf; 556%32=12 -> no bank conflicts (R3-R12)

__device__ __forceinline__ void gl2lds16(const void* g, void* l) {
    __builtin_amdgcn_global_load_lds(
        (const __attribute__((address_space(1))) void*)g,
        (__attribute__((address_space(3))) void*)l, 16, 0, 0);
}

__device__ __forceinline__ void nt_store4(f32x4 v, float* p) {
    __builtin_nontemporal_store(v, (f32x4*)p);
}

// ---------------- DPP-based wave(64) reductions ----------------
template <int CTRL, int RM>
__device__ __forceinline__ float dpp_zero(float x) {
    return __builtin_bit_cast(float, __builtin_amdgcn_update_dpp(
        0, __builtin_bit_cast(int, x), CTRL, RM, 0xf, false));
}
template <int CTRL, int RM>
__device__ __forceinline__ float dpp_self(float x) {
    int xi = __builtin_bit_cast(int, x);
    return __builtin_bit_cast(float, __builtin_amdgcn_update_dpp(xi, xi, CTRL, RM, 0xf, false));
}
__device__ __forceinline__ float wave_bcast63(float x) {
    return __builtin_bit_cast(float, __builtin_amdgcn_readlane(__builtin_bit_cast(int, x), 63));
}
__device__ __forceinline__ float wave_sum(float x) {
    x += dpp_zero<0x111, 0xf>(x);
    x += dpp_zero<0x112, 0xf>(x);
    x += dpp_zero<0x114, 0xf>(x);
    x += dpp_zero<0x118, 0xf>(x);
    x += dpp_zero<0x142, 0xa>(x);
    x += dpp_zero<0x143, 0xc>(x);
    return wave_bcast63(x);
}
__device__ __forceinline__ float wave_fmax(float x) {
    x = fmaxf(x, dpp_self<0x111, 0xf>(x));
    x = fmaxf(x, dpp_self<0x112, 0xf>(x));
    x = fmaxf(x, dpp_self<0x114, 0xf>(x));
    x = fmaxf(x, dpp_self<0x118, 0xf>(x));
    x = fmaxf(x, dpp_self<0x142, 0xa>(x));
    x = fmaxf(x, dpp_self<0x143, 0xc>(x));
    return wave_bcast63(x);
}

// ---------------- fused fp32 -> bf16 convert for all 5 inputs (float4 granules) ----------------
__global__ void cvt_all(const float* __restrict__ hid, const float* __restrict__ wq,
                        const float* __restrict__ wk, const float* __restrict__ wv,
                        const float* __restrict__ wo, bf16* __restrict__ bh,
                        bf16* __restrict__ bqkv, bf16* __restrict__ bwo) {
    int i = blockIdx.x * blockDim.x + threadIdx.x;
    const float* src;
    bf16* dst;
    int off;
    if (i < 1048576) { src = hid; dst = bh; off = i; }
    else if (i < 2097152) { src = wq; dst = bqkv; off = i - 1048576; }
    else if (i < 2359296) { src = wk; dst = bqkv + 2048 * 2048; off = i - 2097152; }
    else if (i < 2621440) { src = wv; dst = bqkv + 2048 * 2048 + 512 * 2048; off = i - 2359296; }
    else { src = wo; dst = bwo; off = i - 2621440; }
    float4 f = ((const float4*)src)[off];
    bf16x4 o;
    o[0] = (bf16)f.x; o[1] = (bf16)f.y; o[2] = (bf16)f.z; o[3] = (bf16)f.w;
    ((bf16x4*)dst)[off] = o;
}

// ---------------- QKV GEMM (64x128, dbuf) with FUSED RoPE + V-transpose epilogue --------
// R9-proven (best measured rest). grid (32,24) = 768 blocks = 3/CU balanced.
__global__ __launch_bounds__(256) void gemm_qkv_rope(const bf16* __restrict__ A,
                                                     const bf16* __restrict__ B,
                                                     const float* __restrict__ cosb,
                                                     const float* __restrict__ sinb,
                                                     bf16* __restrict__ qs,
                                                     bf16* __restrict__ kb,
                                                     bf16* __restrict__ vT) {
    constexpr int BM = 64, BN = 128, K = DM;
    __shared__ bf16 As[2][BM * 32];
    __shared__ bf16 Bs[2][BN * 32];
    __shared__ float ct[32][129];
    int m0 = blockIdx.x * BM;
    int by = blockIdx.y;
    int n0 = by * BN;
    int t = threadIdx.x;
    int l = t & 63, w = t >> 6;
    int lane16 = l & 15, quad = l >> 4;

    const bf16* Abase = A + (size_t)m0 * K;
    const bf16* Bbase = B + (size_t)n0 * K;

    constexpr int MI = BM / 32, NI = BN / 32;
    int wm = (w & 1) * (BM / 2), wn = (w >> 1) * (BN / 2);
    f32x4 acc[MI][NI];
#pragma unroll
    for (int i = 0; i < MI; i++)
#pragma unroll
        for (int j = 0; j < NI; j++) acc[i][j] = (f32x4){0.f, 0.f, 0.f, 0.f};

    constexpr int AG = BM * 4;
    constexpr int BG = BN * 4;

    auto stage = [&](int sel, int k0) {
#pragma unroll
        for (int it = 0; it < AG / 256; it++) {
            int c = it * 256 + t;
            gl2lds16(Abase + (size_t)(c >> 2) * K + k0 + (c & 3) * 8, &As[sel][(c - l) * 8]);
        }
#pragma unroll
        for (int it = 0; it < BG / 256; it++) {
            int c = it * 256 + t;
            gl2lds16(Bbase + (size_t)(c >> 2) * K + k0 + (c & 3) * 8, &Bs[sel][(c - l) * 8]);
        }
    };

    stage(0, 0);
    __syncthreads();
    int cur = 0;
    for (int k0 = 0; k0 < K; k0 += 32) {
        if (k0 + 32 < K) stage(cur ^ 1, k0 + 32);
        bf16x8 af[MI], bfr[NI];
#pragma unroll
        for (int i = 0; i < MI; i++)
            af[i] = *(const bf16x8*)&As[cur][(wm + i * 16 + lane16) * 32 + quad * 8];
#pragma unroll
        for (int j = 0; j < NI; j++)
            bfr[j] = *(const bf16x8*)&Bs[cur][(wn + j * 16 + lane16) * 32 + quad * 8];
#pragma unroll
        for (int i = 0; i < MI; i++)
#pragma unroll
            for (int j = 0; j < NI; j++)
                acc[i][j] = __builtin_amdgcn_mfma_f32_16x16x32_bf16(af[i], bfr[j], acc[i][j], 0, 0, 0);
        __syncthreads();
        cur ^= 1;
    }

    // ---- epilogue: two 32-row halves through LDS ----
#pragma unroll
    for (int half = 0; half < 2; half++) {
        if ((w & 1) == half) {
#pragma unroll
            for (int i = 0; i < MI; i++)
#pragma unroll
                for (int j = 0; j < NI; j++)
#pragma unroll
                    for (int r = 0; r < 4; r++)
                        ct[i * 16 + quad * 4 + r][wn + j * 16 + lane16] = acc[i][j][r];
        }
        __syncthreads();
        if (by < 20) {
#pragma unroll
            for (int it = 0; it < 16; it++) {
                int idx = it * 256 + t;
                int row = idx >> 7, d = idx & 127;
                int s = m0 + half * 32 + row;
                float v = ct[row][d];
                float other = ct[row][(d < 64) ? (d + 64) : (d - 64)];
                float c = cosb[s * HD + d], sn = sinb[s * HD + d];
                float rot = (d < 64) ? -other : other;
                float o = v * c + rot * sn;
                if (by < 16)
                    qs[((size_t)by * S + s) * HD + d] = (bf16)(o * 0.04419417382415922f);
                else
                    kb[((size_t)(by - 16) * S + s) * HD + d] = (bf16)o;
            }
        } else {
            int y0 = (by - 20) * 128;
#pragma unroll
            for (int it = 0; it < 16; it++) {
                int idx = it * 256 + t;
                int y = idx >> 5, ss = idx & 31;
                vT[(size_t)(y0 + y) * S + m0 + half * 32 + ss] = (bf16)ct[ss][y];
            }
        }
        __syncthreads();
    }
}

// ---------------- WO GEMM: 64x128 dbuf (R9-proven) ----------------
template <int BM, int BN>
__global__ __launch_bounds__(256) void gemm_bt(const bf16* __restrict__ A,
                                               const bf16* __restrict__ B,
                                               float* __restrict__ C, int Ndim, int K) {
    __shared__ bf16 As[2][BM * 32];
    __shared__ bf16 Bs[2][BN * 32];
    int m0 = blockIdx.x * BM, n0 = blockIdx.y * BN;
    int t = threadIdx.x;
    int l = t & 63, w = t >> 6;
    int lane16 = l & 15, quad = l >> 4;

    const bf16* Abase = A + (size_t)m0 * K;
    const bf16* Bbase = B + (size_t)n0 * K;

    constexpr int MI = BM / 32, NI = BN / 32;
    int wm = (w & 1) * (BM / 2), wn = (w >> 1) * (BN / 2);
    f32x4 acc[MI][NI];
#pragma unroll
    for (int i = 0; i < MI; i++)
#pragma unroll
        for (int j = 0; j < NI; j++) acc[i][j] = (f32x4){0.f, 0.f, 0.f, 0.f};

    constexpr int AG = BM * 4;
    constexpr int BG = BN * 4;

    auto stage = [&](int sel, int k0) {
#pragma unroll
        for (int it = 0; it < AG / 256; it++) {
            int c = it * 256 + t;
            gl2lds16(Abase + (size_t)(c >> 2) * K + k0 + (c & 3) * 8, &As[sel][(c - l) * 8]);
        }
#pragma unroll
        for (int it = 0; it < BG / 256; it++) {
            int c = it * 256 + t;
            gl2lds16(Bbase + (size_t)(c >> 2) * K + k0 + (c & 3) * 8, &Bs[sel][(c - l) * 8]);
        }
    };

    stage(0, 0);
    __syncthreads();
    int cur = 0;
    for (int k0 = 0; k0 < K; k0 += 32) {
        if (k0 + 32 < K) stage(cur ^ 1, k0 + 32);
        bf16x8 af[MI], bfr[NI];
#pragma unroll
        for (int i = 0; i < MI; i++)
            af[i] = *(const bf16x8*)&As[cur][(wm + i * 16 + lane16) * 32 + quad * 8];
#pragma unroll
        for (int j = 0; j < NI; j++)
            bfr[j] = *(const bf16x8*)&Bs[cur][(wn + j * 16 + lane16) * 32 + quad * 8];
#pragma unroll
        for (int i = 0; i < MI; i++)
#pragma unroll
            for (int j = 0; j < NI; j++)
                acc[i][j] = __builtin_amdgcn_mfma_f32_16x16x32_bf16(af[i], bfr[j], acc[i][j], 0, 0, 0);
        __syncthreads();
        cur ^= 1;
    }
#pragma unroll
    for (int i = 0; i < MI; i++)
#pragma unroll
        for (int j = 0; j < NI; j++) {
            float* cp = C + (size_t)(m0 + wm + i * 16 + quad * 4) * Ndim + n0 + wn + j * 16 + lane16;
#pragma unroll
            for (int r = 0; r < 4; r++) cp[(size_t)r * Ndim] = acc[i][j][r];
        }
}

// ------- fused attn: R9 solver (AS3+NW3, verified absmax 0.01757812) + R12's fused
// row-max (numerically identical: same values, reduced in Phase A readback where they
// are already in registers -> saves the standalone max sweep honestly). R12's AS2+NW2
// degraded absmax to 0.0488 (under-converged support) and gained <8 us -> reverted.
template <int SEGS>
__device__ __forceinline__ void attn_body(const bf16* __restrict__ qs, const bf16* __restrict__ kb,
                                          const bf16* __restrict__ vT, float* __restrict__ attn,
                                          bf16* __restrict__ o, int r0, int h,
                                          float (&buf)[16][BROW]) {
    constexpr int NREG2 = SEGS * 4;  // f32x2 regs per lane (= SEGS*8 scores)
    int jlen = r0 + 16;
    int l = threadIdx.x & 63;
    int w = threadIdx.x >> 6;  // 0..15
    int lane16 = l & 15, quad = l >> 4;

    const bf16* qrow = qs + ((size_t)h * S + (r0 + lane16)) * HD + quad * 8;
    bf16x8 afrag[4];
#pragma unroll
    for (int kc = 0; kc < 4; kc++) afrag[kc] = *(const bf16x8*)(qrow + kc * 32);

    const bf16* kbase = kb + (size_t)(h >> 2) * S * HD;
    const bf16* vbase = vT + (size_t)(h >> 2) * HD * S;
    f32x2 xr[NREG2];
    float mx = -1e30f;  // row max, fused into Phase A readback

    // ---- Phase A: scores into registers; single f32 buffer, 2 barriers/segment ----
#pragma unroll
    for (int sgi = 0; sgi < SEGS; sgi++) {
        int j0 = sgi * 512;
#pragma unroll
        for (int tt = 0; tt < 2; tt++) {
            int t = w + tt * 16;
            int jt = j0 + t * 16;
            if (jt < jlen) {
                f32x4 acc = {0.f, 0.f, 0.f, 0.f};
                const bf16* kp = kbase + (size_t)(jt + lane16) * HD + quad * 8;
#pragma unroll
                for (int kc = 0; kc < 4; kc++) {
                    bf16x8 b = *(const bf16x8*)(kp + kc * 32);
                    acc = __builtin_amdgcn_mfma_f32_16x16x32_bf16(afrag[kc], b, acc, 0, 0, 0);
                }
                if (jt + 15 > r0) {  // diagonal tile: apply causal mask
                    int jj = jt + lane16;
#pragma unroll
                    for (int r = 0; r < 4; r++) {
                        int rowi = quad * 4 + r;
                        float v = acc[r];
                        if (jj > r0 + rowi) v = -1e30f;
                        buf[rowi][t * 16 + lane16] = v;
                    }
                } else {
#pragma unroll
                    for (int r = 0; r < 4; r++) buf[quad * 4 + r][t * 16 + lane16] = acc[r];
                }
            }
        }
        __syncthreads();
#pragma unroll
        for (int part = 0; part < 2; part++) {
            float4 fq = *(const float4*)&buf[w][part * 256 + l * 4];
            f32x2 lo, hi;
            if (sgi == SEGS - 1) {
                int jb = j0 + part * 256 + l * 4;
                lo = (f32x2){(jb + 0 < jlen) ? fq.x : -1e30f, (jb + 1 < jlen) ? fq.y : -1e30f};
                hi = (f32x2){(jb + 2 < jlen) ? fq.z : -1e30f, (jb + 3 < jlen) ? fq.w : -1e30f};
            } else {
                lo = (f32x2){fq.x, fq.y};
                hi = (f32x2){fq.z, fq.w};
            }
            mx = fmaxf(mx, fmaxf(fmaxf(lo[0], lo[1]), fmaxf(hi[0], hi[1])));
            xr[sgi * 4 + part * 2 + 0] = lo;
            xr[sgi * 4 + part * 2 + 1] = hi;
        }
        __syncthreads();
    }

    float* arow = attn + ((size_t)h * S + (r0 + w)) * S;

    // ---- Phase E (early; tau-independent): zero-fill strictly-upper region ----
    {
        f32x4 z4 = {0.f, 0.f, 0.f, 0.f};
        for (int j = SEGS * 512 + l * 4; j < S; j += 256) nt_store4(z4, &arow[j]);
    }

    // ---- Phase B: entmax-1.5 tau: 3 active-set steps + 3 Newton polish ----
    const f32x2 z2 = {0.f, 0.f};
    float m = wave_fmax(mx);
    float taulo = m - 1.0f;
    float tauhi = m - 0.02209709f;  // m - (1/2048)^0.5
    float tau = taulo;

#pragma unroll 1
    for (int it = 0; it < AS_ITERS; it++) {
        f32x2 tvi = {tau, tau};
        f32x2 b1a = z2, b1b = z2, b2a = z2, b2b = z2, cna = z2, cnb = z2;
#pragma unroll
        for (int c = 0; c < NREG2; c += 2) {
            f32x2 t0 = __builtin_elementwise_max(xr[c] - tvi, z2);
            b2a += t0 * t0; b1a += t0;
            cna += (f32x2){t0[0] > 0.f ? 1.f : 0.f, t0[1] > 0.f ? 1.f : 0.f};
            f32x2 t1 = __builtin_elementwise_max(xr[c + 1] - tvi, z2);
            b2b += t1 * t1; b1b += t1;
            cnb += (f32x2){t1[0] > 0.f ? 1.f : 0.f, t1[1] > 0.f ? 1.f : 0.f};
        }
        f32x2 s1 = b1a + b1b, s2 = b2a + b2b, sc = cna + cnb;
        float B1 = wave_sum(s1[0] + s1[1]);
        float B2 = wave_sum(s2[0] + s2[1]);
        float n = wave_sum(sc[0] + sc[1]);
        float disc = fmaxf(B1 * B1 - n * (B2 - 1.0f), 0.f);
        tau += (B1 - __builtin_sqrtf(disc)) / fmaxf(n, 1.0f);
        tau = fminf(fmaxf(tau, taulo), tauhi);
    }
#pragma unroll 1
    for (int it = 0; it < NW_ITERS; it++) {
        f32x2 tvi = {tau, tau};
        f32x2 fa = z2, fb = z2, ga = z2, gb = z2;
#pragma unroll
        for (int c = 0; c < NREG2; c += 2) {
            f32x2 t0 = __builtin_elementwise_max(xr[c] - tvi, z2);
            fa += t0 * t0; ga += t0;
            f32x2 t1 = __builtin_elementwise_max(xr[c + 1] - tvi, z2);
            fb += t1 * t1; gb += t1;
        }
        f32x2 fv = fa + fb, gv = ga + gb;
        float f = wave_sum(fv[0] + fv[1]);
        float g = wave_sum(gv[0] + gv[1]);
        tau += (f - 1.0f) / (2.0f * g + 1e-20f);
        tau = fminf(fmaxf(tau, taulo), tauhi);
    }

    f32x2 tv = {tau, tau};
    float inv;
    {
        f32x2 sa = z2, sbv = z2;
#pragma unroll
        for (int c = 0; c < NREG2; c += 2) {
            f32x2 t0 = __builtin_elementwise_max(xr[c] - tv, z2);
            sa += t0 * t0;
            f32x2 t1 = __builtin_elementwise_max(xr[c + 1] - tv, z2);
            sbv += t1 * t1;
        }
        f32x2 sv = sa + sbv;
        float ssum = wave_sum(sv[0] + sv[1]);
        inv = 1.0f / ssum;
    }

    // ---- Phase C: P f32 -> attn global (fused; xr dies here) + P bf16 -> LDS
    //      (ping-pong halves), P.V MFMA; 1 barrier/segment ----
    int jt_o = (w & 7) * 16;
    int kh = (w >> 3) * 256;
    f32x4 acc_o = {0.f, 0.f, 0.f, 0.f};
    f32x2 inv2 = {inv, inv};

#pragma unroll
    for (int sgi = 0; sgi < SEGS; sgi++) {
        int j0 = sgi * 512;
        bf16 (*pb)[BROW] = (bf16(*)[BROW])(&buf[0][0]) + (sgi & 1) * 16;
#pragma unroll
        for (int part = 0; part < 2; part++) {
            f32x2 ta = __builtin_elementwise_max(xr[sgi * 4 + part * 2 + 0] - tv, z2);
            f32x2 tb = __builtin_elementwise_max(xr[sgi * 4 + part * 2 + 1] - tv, z2);
            f32x2 pa = (ta * ta) * inv2;
            f32x2 pb2 = (tb * tb) * inv2;
            f32x4 pv = {pa[0], pa[1], pb2[0], pb2[1]};
            nt_store4(pv, &arow[j0 + part * 256 + l * 4]);
            bf16x4 pbv;
            pbv[0] = (bf16)pv[0]; pbv[1] = (bf16)pv[1];
            pbv[2] = (bf16)pv[2]; pbv[3] = (bf16)pv[3];
            *(bf16x4*)&pb[w][part * 256 + l * 4] = pbv;
        }
        __syncthreads();
#pragma unroll
        for (int ks = 0; ks < 8; ks++) {
            int kk = kh + ks * 32;
            bf16x8 a = *(const bf16x8*)&pb[lane16][kk + quad * 8];
            bf16x8 b = *(const bf16x8*)(vbase + (size_t)(jt_o + lane16) * S + j0 + kk + quad * 8);
            acc_o = __builtin_amdgcn_mfma_f32_16x16x32_bf16(a, b, acc_o, 0, 0, 0);
        }
    }

    // ---- Phase D: combine K-halves, write O ----
    __syncthreads();
    if (w >= 8) {
#pragma unroll
        for (int r = 0; r < 4; r++) buf[w - 8][l * 4 + r] = acc_o[r];
    }
    __syncthreads();
    if (w < 8) {
        bf16* op = o + (size_t)(r0 + quad * 4) * DM + h * HD + jt_o + lane16;
#pragma unroll
        for (int r = 0; r < 4; r++) {
            float v = acc_o[r] + buf[w][l * 4 + r];
            op[(size_t)r * DM] = (bf16)v;
        }
    }
}

// 512 persistent blocks (2/CU), classes {4,3,2,1} = 10 segments/block, uniform.
__global__ __launch_bounds__(1024, 8) void attn_av_all(const bf16* __restrict__ qs,
                                                       const bf16* __restrict__ kb,
                                                       const bf16* __restrict__ vT,
                                                       float* __restrict__ attn,
                                                       bf16* __restrict__ o) {
    __shared__ float buf[16][BROW];
    int b = blockIdx.x;
    int h = b & 15;
    int qh = b >> 4;
    attn_body<4>(qs, kb, vT, attn, o, (96 + qh) * 16, h, buf);
    __syncthreads();
    attn_body<3>(qs, kb, vT, attn, o, (64 + qh) * 16, h, buf);
    __syncthreads();
    attn_body<2>(qs, kb, vT, attn, o, (32 + qh) * 16, h, buf);
    __syncthreads();
    attn_body<1>(qs, kb, vT, attn, o, qh * 16, h, buf);
}

extern "C" void kernel_launch(void* const* d_in, const int* in_sizes, int n_in,
                              void* d_out, int out_size, void* d_ws, size_t ws_size,
                              hipStream_t stream) {
    const float* hidden = (const float*)d_in[0];
    const float* cosb   = (const float*)d_in[1];
    const float* sinb   = (const float*)d_in[2];
    const float* wq     = (const float*)d_in[3];
    const float* wk     = (const float*)d_in[4];
    const float* wv     = (const float*)d_in[5];
    const float* wo     = (const float*)d_in[6];
    char* ws = (char*)d_ws;
    bf16*  bf_hidden = (bf16*)(ws);                    // 8 MB; reused as O bf16 later
    bf16*  bf_wqkv   = (bf16*)(ws + 8388608);          // 12 MB
    bf16*  bf_wo     = (bf16*)(ws + 20971520);         // 8 MB
    bf16*  qsb       = (bf16*)(ws + 29360128);         // 8 MB  [H][S][HD]
    bf16*  kbb       = (bf16*)(ws + 37748736);         // 2 MB  [4][S][HD]
    bf16*  vTb       = (bf16*)(ws + 39845888);         // 2 MB  [4][HD][S]
    float* out  = (float*)d_out;
    float* attn = out + 4194304;

    cvt_all<<<dim3(14336), 256, 0, stream>>>(hidden, wq, wk, wv, wo, bf_hidden, bf_wqkv, bf_wo);

    // QKV projection with fused RoPE + V-transpose epilogue (768 blocks = 3/CU balanced)
    gemm_qkv_rope<<<dim3(32, 24), 256, 0, stream>>>(bf_hidden, bf_wqkv, cosb, sinb,
                                                    qsb, kbb, vTb);

    // fused scores + entmax + P.V + attn write  (512 persistent blocks, 2/CU)
    attn_av_all<<<dim3(512), 1024, 0, stream>>>(qsb, kbb, vTb, attn, bf_hidden);

    // out = O @ wo^T  (512 blocks = 2/CU balanced)
    gemm_bt<64, 128><<<dim3(32, 16), 256, 0, stream>>>(bf_hidden, bf_wo, out, DM, DM);
}